// Round 9
// baseline (87.343 us; speedup 1.0000x reference)
//
#include <hip/hip_runtime.h>

static constexpr int  D   = 64;        // embedding dim (C)
static constexpr int  KC  = 1024;      // codebook size
static constexpr int  HW  = 4096;      // 64*64
static constexpr long QSZ = 16L*64*64*64;  // elems per output tensor
static constexpr float GAPT = 0.025f;  // acc-domain gap; f16 2-term err sigma ~2.2e-3 -> 11 sigma

// ---- d_ws layout (bytes) ----
static constexpr size_t WS_ENORM = 0;        // f32[1024] +sum e^2 (recheck)
static constexpr size_t REC      = 4352;     // per-16-col chunk record:
                                             //  [0,2048)  Eh f16 [g8][col16][8]
                                             //  [2048,4096) El f16 same layout
                                             //  [4096,4160) en f32[16] = -0.5*||e||^2
                                             //  [4160,4352) pad (stage reads 256B tail)
static constexpr size_t WS_ES    = 4096;     // 64 records = 278528 B
static constexpr size_t WS_CNT   = WS_ES + 64 * REC;   // 282624
static constexpr size_t WS_LIST  = WS_CNT + 4;
static constexpr size_t WS_NEED  = WS_LIST + 65536 * 4;

typedef __attribute__((ext_vector_type(8))) _Float16 f16x8;  // 8 f16 (4 VGPR)
typedef __attribute__((ext_vector_type(4))) float    f32x4;  // MFMA C/D

__device__ __forceinline__ void gload_lds16(const void* g, void* l) {
  __builtin_amdgcn_global_load_lds(
      (const __attribute__((address_space(1))) void*)g,
      (__attribute__((address_space(3))) void*)l, 16, 0, 0);
}
__device__ __forceinline__ void gload_lds4(const void* g, void* l) {
  __builtin_amdgcn_global_load_lds(
      (const __attribute__((address_space(1))) void*)g,
      (__attribute__((address_space(3))) void*)l, 4, 0, 0);
}

// ---------------------------------------------------------------------------
// prep: f16 hi/lo split of E + (-0.5*||e||^2) into chunk records; enorm; cnt=0
// ---------------------------------------------------------------------------
__global__ void __launch_bounds__(64) prep_kernel(const float* __restrict__ E,
                                                  float* __restrict__ enorm,
                                                  char* __restrict__ Es,
                                                  int* __restrict__ cnt) {
  const int k = blockIdx.x, c = threadIdx.x;
  if (k == 0 && c == 0) *cnt = 0;
  const float v = E[k * D + c];
  const _Float16 hx = (_Float16)v;
  const float    r  = v - (float)hx;   // exact (Sterbenz)
  const _Float16 lx = (_Float16)r;
  char* rec = Es + (size_t)(k >> 4) * REC;
  const int col = k & 15, g = c >> 3, j = c & 7;
  *(_Float16*)(rec +        2 * (g * 128 + col * 8 + j)) = hx;
  *(_Float16*)(rec + 2048 + 2 * (g * 128 + col * 8 + j)) = lx;
  float s = v * v;
#pragma unroll
  for (int off = 32; off; off >>= 1) s += __shfl_down(s, off, 64);
  if (c == 0) { enorm[k] = s; *(float*)(rec + 4096 + col * 4) = -0.5f * s; }
}

// ---------------------------------------------------------------------------
// main kernel: 4096 blocks x 64 thr (1 wave). Block = (row-tile rt, quarter qa):
// 64 rows (mi=4) x 256 cols. Wave-PRIVATE LDS double-buffer staged via
// global_load_lds + counted s_waitcnt vmcnt(5) -- NO barriers in the loop
// (hardware prefetch queue; no cross-wave hazards). f16 2-term split:
// acc = -0.5||e||^2 + fh.(eh+el); score = -2*acc (argMAX). Per-quarter top-2
// partials stored into row's own lat-region slot of out (finalize merges).
// ---------------------------------------------------------------------------
__global__ void __launch_bounds__(64)
vq_mfma_kernel(const float* __restrict__ X,
               const char* __restrict__ Es,
               float* __restrict__ out) {
  __shared__ __attribute__((aligned(16))) char Bs[2][4352];

  const int lane = threadIdx.x;
  const int c15  = lane & 15;
  const int kg   = lane >> 4;
  const int blk  = blockIdx.x;        // 4096
  const int qa   = blk & 3;           // col quarter
  const int rt   = blk >> 2;          // row tile 0..1023 = (bb<<6)|h
  const int bb   = rt >> 6;
  const int h    = rt & 63;

  // ---- A-fragments: direct global transpose-pattern loads (L1/L2-hot) ----
  const float* __restrict__ xb = X + (size_t)bb * (D * HW) + h * 64;
  f16x8 ah[4][2];
#pragma unroll
  for (int mi = 0; mi < 4; ++mi)
#pragma unroll
    for (int ks = 0; ks < 2; ++ks) {
      f16x8 v;
#pragma unroll
      for (int j = 0; j < 8; ++j)
        v[j] = (_Float16)xb[(ks * 32 + kg * 8 + j) * HW + mi * 16 + c15];
      ah[mi][ks] = v;
    }

  // ---- prologue: stage chunks 0,1 (5 loads each -> 10 outstanding) ----
  const char* __restrict__ EsQ = Es + (size_t)(qa * 16) * REC;
  {
#pragma unroll
    for (int ch = 0; ch < 2; ++ch) {
      const char* src = EsQ + (size_t)ch * REC;
      char* dst = &Bs[ch][0];
#pragma unroll
      for (int is = 0; is < 4; ++is)
        gload_lds16(src + is * 1024 + lane * 16, dst + is * 1024);
      gload_lds4(src + 4096 + lane * 4, dst + 4096);
    }
  }
  __builtin_amdgcn_sched_barrier(0);

  float b1[4][4], b2[4][4]; int i1[4][4];
#pragma unroll
  for (int mi = 0; mi < 4; ++mi)
#pragma unroll
    for (int r = 0; r < 4; ++r) { b1[mi][r] = -3.4e38f; b2[mi][r] = -3.4e38f; i1[mi][r] = 0; }

  const int eo = 2 * (kg * 128 + c15 * 8);
#pragma unroll 2
  for (int t = 0; t < 16; ++t) {
    // wait for chunk t's 5 staging loads (chunk t+1's 5 may stay in flight)
    if (t < 15) asm volatile("s_waitcnt vmcnt(5)" ::: "memory");
    else        asm volatile("s_waitcnt vmcnt(0)" ::: "memory");
    __builtin_amdgcn_sched_barrier(0);
    const char* bp = &Bs[t & 1][0];
    const f16x8 h0 = *(const f16x8*)(bp + eo);
    const f16x8 h1 = *(const f16x8*)(bp + eo + 1024);        // (kg+4) group
    const f16x8 l0 = *(const f16x8*)(bp + 2048 + eo);
    const f16x8 l1 = *(const f16x8*)(bp + 2048 + eo + 1024);
    const float en = *(const float*)(bp + 4096 + c15 * 4);   // broadcast read
    const int col = (qa << 8) + (t << 4) + c15;              // ascending in t
#pragma unroll
    for (int mi = 0; mi < 4; ++mi) {
      f32x4 acc = {en, en, en, en};
      acc = __builtin_amdgcn_mfma_f32_16x16x32_f16(ah[mi][0], h0, acc, 0, 0, 0);
      acc = __builtin_amdgcn_mfma_f32_16x16x32_f16(ah[mi][1], h1, acc, 0, 0, 0);
      acc = __builtin_amdgcn_mfma_f32_16x16x32_f16(ah[mi][0], l0, acc, 0, 0, 0);
      acc = __builtin_amdgcn_mfma_f32_16x16x32_f16(ah[mi][1], l1, acc, 0, 0, 0);
#pragma unroll
      for (int r = 0; r < 4; ++r) {
        const float x  = acc[r];
        const bool  gt = x > b1[mi][r];
        b2[mi][r] = __builtin_amdgcn_fmed3f(b2[mi][r], x, b1[mi][r]);  // 2nd
        b1[mi][r] = gt ? x   : b1[mi][r];
        i1[mi][r] = gt ? col : i1[mi][r];
      }
    }
    __builtin_amdgcn_sched_barrier(0);
    if (t < 14) {   // stage chunk t+2 into the buffer just consumed
      const char* src = EsQ + (size_t)(t + 2) * REC;
      char* dst = &Bs[t & 1][0];
#pragma unroll
      for (int is = 0; is < 4; ++is)
        gload_lds16(src + is * 1024 + lane * 16, dst + is * 1024);
      gload_lds4(src + 4096 + lane * 4, dst + 4096);
    }
  }

  // ---- merge top-2 across the 16 col-lanes; store per-quarter partials ----
  // partial slot for row n, quarter qa lives INSIDE lat row n (overwritten by
  // finalize after it reads them): 16B at out[QSZ + n*64 + qa*4].
  float* __restrict__ P = out + QSZ;
#pragma unroll
  for (int mi = 0; mi < 4; ++mi) {
#pragma unroll
    for (int r = 0; r < 4; ++r) {
      float B1 = b1[mi][r], B2 = b2[mi][r]; int I1 = i1[mi][r];
#pragma unroll
      for (int m = 1; m < 16; m <<= 1) {
        const float o1 = __shfl_xor(B1, m, 64);
        const float o2 = __shfl_xor(B2, m, 64);
        const int   oi = __shfl_xor(I1, m, 64);
        const float n2 = fmaxf(fmaxf(B2, o2), fminf(B1, o1));
        if (o1 > B1) { B1 = o1; I1 = oi; }
        B2 = n2;
      }
      if (c15 == 0) {
        const size_t n = (size_t)rt * 64 + mi * 16 + kg * 4 + r;
        float4 rec;
        rec.x = B1; rec.y = B2; rec.z = __int_as_float(I1); rec.w = 0.f;
        *(float4*)(P + n * 64 + qa * 4) = rec;
      }
    }
  }
}

// ---------------------------------------------------------------------------
// finalize: merge 4 quarter-partials per row (ascending quarter order), flag
// near-ties, then the proven transpose-output phases. 512 blocks x 256 thr,
// block = 128 rows. Reads partials BEFORE overwriting lat (barrier-ordered).
// ---------------------------------------------------------------------------
__global__ void __launch_bounds__(256)
finalize_kernel(const float* __restrict__ X,
                const float* __restrict__ E,
                float* __restrict__ out,
                int* __restrict__ cnt,
                int* __restrict__ list) {
  __shared__ float Xt[128][66];
  __shared__ int idx_s[128];

  const int tid = threadIdx.x;
  const int blk = blockIdx.x;          // 512
  const int bb  = blk >> 5;
  const int h0  = (blk & 31) * 2;
  const size_t n0 = (size_t)blk * 128;
  float* __restrict__ P = out + QSZ;   // lat region holds partials

  if (tid < 128) {
    const size_t n = n0 + tid;
    const float* pp = P + n * 64;
    float g1, g2; int gi;
    {
      const float4 q = *(const float4*)(pp);
      g1 = q.x; g2 = q.y; gi = __float_as_int(q.z);
    }
#pragma unroll
    for (int qq = 1; qq < 4; ++qq) {
      const float4 q = *(const float4*)(pp + qq * 4);
      const float s1 = q.x, s2 = q.y; const int ii = __float_as_int(q.z);
      if (s1 > g1) { g2 = fmaxf(g1, s2); g1 = s1; gi = ii; }
      else         { g2 = fmaxf(g2, s1); }
    }
    idx_s[tid] = gi;
    if (g1 - g2 < GAPT) {                // near-tie -> exact recheck
      const int pos = atomicAdd(cnt, 1);
      if (pos < 65536) list[pos] = (int)n;
    }
  }
  __syncthreads();

  // stage 128x64 X-slice transposed
  const float* __restrict__ xbase = X + (size_t)bb * (D * HW) + h0 * 64;
  {
    const int w = tid & 63, c0 = tid >> 6;
#pragma unroll
    for (int hh = 0; hh < 2; ++hh)
#pragma unroll
      for (int i = 0; i < 16; ++i)
        Xt[hh * 64 + w][c0 + i * 4] = xbase[(c0 + i * 4) * HW + hh * 64 + w];
  }
  __syncthreads();

  float* __restrict__ lat = out + QSZ;
  float* __restrict__ ql  = out + 2 * QSZ;
#pragma unroll
  for (int i = 0; i < 32; ++i) {
    const int e_ = i * 256 + tid;
    const int w = e_ >> 6, c = e_ & 63;
    const float q = E[idx_s[w] * D + c];    // coalesced gather (w uniform/group)
    ql[(n0 + w) * D + c]  = q;
    lat[(n0 + w) * D + c] = Xt[w][c];
    Xt[w][c] = q;                            // overlay for quantized pass
  }
  __syncthreads();
  float* __restrict__ qb = out + (size_t)bb * (D * HW) + h0 * 64;
#pragma unroll
  for (int i = 0; i < 32; ++i) {
    const int e_ = i * 256 + tid;
    const int c = e_ >> 7, rl = e_ & 127;
    qb[c * HW + rl] = Xt[rl][c];            // coalesced over rl
  }
}

// ---------------------------------------------------------------------------
// exact fp32 recheck for flagged rows (lowest-index tie-break), 1 wave/row
// ---------------------------------------------------------------------------
__global__ void __launch_bounds__(64) recheck_kernel(const float* __restrict__ X,
                                                     const float* __restrict__ E,
                                                     const float* __restrict__ enorm,
                                                     const int* __restrict__ cnt,
                                                     const int* __restrict__ list,
                                                     float* __restrict__ out) {
  __shared__ float fsh[64];
  const int lane = threadIdx.x;
  const int n = min(*cnt, 65536);
  for (int ii = blockIdx.x; ii < n; ii += gridDim.x) {
    const int row = list[ii];
    const int b = row >> 12, h = (row >> 6) & 63, w = row & 63;
    fsh[lane] = X[((size_t)b * D + lane) * HW + h * 64 + w];
    __syncthreads();
    float best = 3.4e38f; int bidx = 0;
    for (int j = 0; j < 16; ++j) {
      const int k = lane + j * 64;
      const float* __restrict__ e = E + k * D;
      float a0 = 0.f, a1 = 0.f, a2 = 0.f, a3 = 0.f;
#pragma unroll
      for (int c = 0; c < D; c += 4) {
        a0 = fmaf(fsh[c + 0], e[c + 0], a0);
        a1 = fmaf(fsh[c + 1], e[c + 1], a1);
        a2 = fmaf(fsh[c + 2], e[c + 2], a2);
        a3 = fmaf(fsh[c + 3], e[c + 3], a3);
      }
      const float s = enorm[k] - 2.0f * ((a0 + a1) + (a2 + a3));
      if (s < best) { best = s; bidx = k; }
    }
#pragma unroll
    for (int m = 1; m < 64; m <<= 1) {
      const float ob = __shfl_xor(best, m, 64);
      const int   oi = __shfl_xor(bidx, m, 64);
      if (ob < best || (ob == best && oi < bidx)) { best = ob; bidx = oi; }
    }
    const float q = E[bidx * D + lane];
    float* __restrict__ ql = out + 2 * QSZ;
    ql[(size_t)row * D + lane] = q;
    out[((size_t)b * D + lane) * HW + h * 64 + w] = q;
    __syncthreads();
  }
}

// ---------------------------------------------------------------------------
// fallback (R1 kernels) if ws_size is too small for the staged tables
// ---------------------------------------------------------------------------
__global__ void __launch_bounds__(64) enorm_kernel(const float* __restrict__ E,
                                                   float* __restrict__ enorm) {
  const int k = blockIdx.x, c = threadIdx.x;
  float v = E[k * D + c];
  float s = v * v;
#pragma unroll
  for (int off = 32; off; off >>= 1) s += __shfl_down(s, off, 64);
  if (c == 0) enorm[k] = s;
}

__global__ void __launch_bounds__(256) vq_kernel(const float* __restrict__ X,
                                                 const float* __restrict__ E,
                                                 const float* __restrict__ enorm,
                                                 float* __restrict__ out) {
  const int bh = blockIdx.x, b = bh >> 6, h = bh & 63;
  const int tid = threadIdx.x, wave = tid >> 6, lane = tid & 63;
  const float* __restrict__ xbase = X + (size_t)b * (D * HW) + h * 64;
  float f[D];
#pragma unroll
  for (int c = 0; c < D; ++c) f[c] = xbase[c * HW + lane];
  float best = 3.4e38f; int bidx = 0;
  const int k0 = wave * (KC / 4);
  for (int k = k0; k < k0 + (KC / 4); ++k) {
    const float* __restrict__ e = E + k * D;
    float a0 = 0.f, a1 = 0.f, a2 = 0.f, a3 = 0.f;
#pragma unroll
    for (int c = 0; c < D; c += 4) {
      a0 = fmaf(f[c + 0], e[c + 0], a0);
      a1 = fmaf(f[c + 1], e[c + 1], a1);
      a2 = fmaf(f[c + 2], e[c + 2], a2);
      a3 = fmaf(f[c + 3], e[c + 3], a3);
    }
    const float score = enorm[k] - 2.0f * ((a0 + a1) + (a2 + a3));
    if (score < best) { best = score; bidx = k; }
  }
  __shared__ float sc_s[4][64]; __shared__ int id_s[4][64];
  __shared__ int idx_s[64]; __shared__ float tile[64 * 65]; __shared__ float eq[64 * 65];
  sc_s[wave][lane] = best; id_s[wave][lane] = bidx;
  if (wave == 0) {
#pragma unroll
    for (int c = 0; c < D; ++c) tile[c * 65 + lane] = f[c];
  }
  __syncthreads();
  if (tid < 64) {
    float bs = sc_s[0][tid]; int bi = id_s[0][tid];
#pragma unroll
    for (int wv = 1; wv < 4; ++wv) {
      if (sc_s[wv][tid] < bs) { bs = sc_s[wv][tid]; bi = id_s[wv][tid]; }
    }
    idx_s[tid] = bi;
  }
  __syncthreads();
  float* __restrict__ qout = out;
  float* __restrict__ lat = out + QSZ;
  float* __restrict__ ql = out + 2 * QSZ;
  const size_t n0 = (size_t)bh * 64;
#pragma unroll
  for (int i = 0; i < 16; ++i) {
    const int e_ = i * 256 + tid, w = e_ >> 6, c = e_ & 63;
    const float q = E[idx_s[w] * D + c];
    eq[w * 65 + c] = q;
    ql[(n0 + w) * D + c] = q;
    lat[(n0 + w) * D + c] = tile[c * 65 + w];
  }
  __syncthreads();
  float* __restrict__ qb = qout + (size_t)b * (D * HW) + h * 64;
#pragma unroll
  for (int i = 0; i < 16; ++i) {
    const int e_ = i * 256 + tid, c = e_ >> 6, w = e_ & 63;
    qb[c * HW + w] = eq[w * 65 + c];
  }
}

extern "C" void kernel_launch(void* const* d_in, const int* in_sizes, int n_in,
                              void* d_out, int out_size, void* d_ws, size_t ws_size,
                              hipStream_t stream) {
  const float* X = (const float*)d_in[0];
  const float* E = (const float*)d_in[1];
  float* out = (float*)d_out;
  char* ws = (char*)d_ws;

  if (ws_size >= WS_NEED) {
    float* enorm = (float*)(ws + WS_ENORM);
    char*  Es    = ws + WS_ES;
    int* cnt  = (int*)(ws + WS_CNT);
    int* list = (int*)(ws + WS_LIST);
    prep_kernel<<<KC, 64, 0, stream>>>(E, enorm, Es, cnt);
    vq_mfma_kernel<<<4096, 64, 0, stream>>>(X, Es, out);
    finalize_kernel<<<512, 256, 0, stream>>>(X, E, out, cnt, list);
    recheck_kernel<<<1024, 64, 0, stream>>>(X, E, enorm, cnt, list, out);
  } else {
    float* enorm = (float*)ws;
    enorm_kernel<<<KC, 64, 0, stream>>>(E, enorm);
    vq_kernel<<<1024, 256, 0, stream>>>(X, E, enorm, out);
  }
}